// Round 2
// baseline (14.445 us; speedup 1.0000x reference)
//
#include <hip/hip_runtime.h>

// Problem constants (fixed by setup_inputs)
constexpr int N = 2, D = 64, H = 128, W = 128;
constexpr int K = 5, K2 = 25, DIL = 3, PAD = 6;   // pad = (K/2)*DIL
constexpr int DCHUNK = 16;                         // channels per block
constexpr int HW = H * W;
constexpr int VBYTES = N * D * H * W * 4;          // 8388608
constexpr int SKW = 144;                           // skewed s_att row stride (floats)

typedef float float4v __attribute__((ext_vector_type(4)));
typedef float float2v __attribute__((ext_vector_type(2)));

__device__ __forceinline__ int sidx(int w) { return w + 4 * (w >> 5); }

__device__ __forceinline__ void pk_fma(float2v& d, float2v s0, float2v s1) {
    // packed dual FP32 FMA: d.lo += s0.lo*s1.lo ; d.hi += s0.hi*s1.hi
    asm("v_pk_fma_f32 %0, %1, %2, %0" : "+v"(d) : "v"(s0), "v"(s1));
}

// Phase 1, k in [KLO,KHI): batched clamped loads FIRST (one latency exposure),
// then compute. Stores UNNORMALIZED att (0 at OOB; OOB sim term 1+1e-5 still
// counted in the returned partial sum — matches zero-padded im2col reference).
// One thread owns one pixel (128 threads = 128 pixels) -> no cross-thread
// reduction, single barrier.
template<int KLO, int KHI>
__device__ __forceinline__ float phase1_part(const float* __restrict__ bp,
                                             const float* __restrict__ dist,
                                             int h, int w, float* sa) {
    constexpr int KN = KHI - KLO;
    float bvr[KN];
    bool  okk[KN];
#pragma unroll
    for (int kk = 0; kk < KN; ++kk) {
        const int k = KLO + kk, i = k / K, j = k % K;
        int bh = h + i * DIL - PAD;
        int bw = w + j * DIL - PAD;
        okk[kk] = (bh >= 0) & (bh < H) & (bw >= 0) & (bw < W);
        int off = bh * W + bw;
        off = min(max(off, 0), HW - 1);     // v_med3
        bvr[kk] = bp[off];
    }
    float partial = 0.f;
#pragma unroll
    for (int kk = 0; kk < KN; ++kk) {
        const int k = KLO + kk;
        float bv = okk[kk] ? bvr[kk] : 0.f;
        float bm = fminf(fmaxf(bv * dist[k], 0.f), 1.f);
        float s = 1.f - bm + 1e-5f;
        partial += s;
        sa[k * SKW + sidx(w)] = okk[kk] ? s : 0.f;
    }
    return partial;
}

__global__ __launch_bounds__(128, 4)
void infuse_kernel(const float* __restrict__ V,
                   const float* __restrict__ boundary,
                   const float* __restrict__ dist,
                   float* __restrict__ out) {
    // grid = N * H * (D/DCHUNK) = 1024. XCD-chunked bijection (1024 = 8*128):
    // XCD x owns 32 consecutive h -> V slice ~1.3 MB, L2-resident.
    int obid = blockIdx.x;
    int bid  = (obid & 7) * 128 + (obid >> 3);     // bijective
    int dblk = bid & 3;            // channel block (D/DCHUNK = 4)
    int h    = (bid >> 2) & (H - 1);
    int n    = bid >> 9;

    __shared__ float s_att[K2 * SKW];   // 14.4 KB, skewed, UNNORMALIZED
    __shared__ float s_scale[SKW];      // skewed like s_att rows

    int tid = threadIdx.x;

    // ---- Phase 0: phase-2 addressing; prefetch window row 0 so its latency
    // hides under the phase-1 attention compute.
    // Thread = 16 consecutive pixels x 1 channel: 32-float window row loaded
    // as 8 dwordx4 = 128 B for 16 px -> 8 B/elem through L1 (vs 12 B/elem in
    // the 8-px tiling) at unchanged occupancy (8 blocks/CU, 16 wv/CU).
    int g  = tid & 7;              // pixel group: pixels 16g..16g+15
    int c  = tid >> 3;             // channel within chunk (0..15)
    int d  = dblk * DCHUNK + c;
    int gw = 16 * g;
    int sg = sidx(gw);             // 16-float att fragments never cross a pad

    int cb   = (n * D + d) * (H * W * 4);   // channel byte base (fits int)
    int colb = gw * 4 - 32;                  // window base col gw-8, 32B aligned
    const char* Vb = (const char*)V;

    // Clamp invariant (validated): every 16B chunk is either fully inside
    // att=0 window positions or unclamped. With base col gw-8 the only
    // clamping chunks are e=0,1 at cb=0,r=0,gw=0 (cols < 0, att=0) and
    // whole rows r>=128 (att=0). Needed cols gw-6..gw+21 always land
    // unclamped: f = px + 3j + 2 in [2,29] of the 32 loaded floats.
    float4v vbuf[2][8];
    {
        int r  = h - PAD;                    // row for i=0 (may be OOB)
        int rb = cb + r * (W * 4) + colb;
#pragma unroll
        for (int e = 0; e < 8; ++e) {
            int o = rb + 16 * e;
            o = min(max(o, 0), VBYTES - 16);   // v_med3
            vbuf[0][e] = *(const float4v*)(Vb + o);
        }
    }
    __builtin_amdgcn_sched_barrier(0);   // pin: prefetch issued before phase 1

    // ---- Phase 1: 128 threads = 128 pixels, each does all 25 taps.
    {
        int w = tid;
        const float* bp = boundary + n * HW;
        float bc = bp[h * W + w];            // center boundary (for scale)
        float total = phase1_part<0, 13>(bp, dist, h, w, s_att)
                    + phase1_part<13, 25>(bp, dist, h, w, s_att);
        s_scale[sidx(w)] = (1.f - bc) / total;
    }
    __syncthreads();

    // ---- Phase 2: 1-deep row software pipeline; acc held as 8 float2 pairs.
    float2v acc2[8] = {{0,0},{0,0},{0,0},{0,0},{0,0},{0,0},{0,0},{0,0}};

#pragma unroll
    for (int i = 0; i < K; ++i) {
        // issue next row's loads before consuming the current row
        if (i < K - 1) {
            int r  = h + (i + 1) * DIL - PAD;
            int rb = cb + r * (W * 4) + colb;
#pragma unroll
            for (int e = 0; e < 8; ++e) {
                int o = rb + 16 * e;
                o = min(max(o, 0), VBYTES - 16);   // v_med3
                vbuf[(i + 1) & 1][e] = *(const float4v*)(Vb + o);
            }
        }
        const float4v (&v)[8] = vbuf[i & 1];   // static index after unroll

#pragma unroll
        for (int j = 0; j < K; ++j) {
            const float* ap = &s_att[(i * K + j) * SKW + sg];
            float4v aa[4];
            aa[0] = *(const float4v*)ap;
            aa[1] = *(const float4v*)(ap + 4);
            aa[2] = *(const float4v*)(ap + 8);
            aa[3] = *(const float4v*)(ap + 12);
            // v float f corresponds to col gw-8+f; tap (j,px) needs f=px+3j+2
            if ((j & 1) == 0) {
                // even j: idx = 2pp + 3j + 2 is even -> adjacent v pairs
#pragma unroll
                for (int pp = 0; pp < 8; ++pp) {
                    const int idx = 2 * pp + 3 * j + 2;   // compile-time, even
                    float2v s0 = {v[idx >> 2][idx & 3],
                                  v[(idx + 1) >> 2][(idx + 1) & 3]};
                    float2v av = {aa[pp >> 1][(2 * pp) & 3],
                                  aa[pp >> 1][(2 * pp + 1) & 3]};
                    pk_fma(acc2[pp], s0, av);
                }
            } else {
                // odd j: misaligned pairs -> scalar
#pragma unroll
                for (int px = 0; px < 16; ++px) {
                    const int idx = px + 3 * j + 2;
                    float a = aa[px >> 2][px & 3];
                    acc2[px >> 1][px & 1] =
                        fmaf(v[idx >> 2][idx & 3], a, acc2[px >> 1][px & 1]);
                }
            }
        }
    }

    // apply per-pixel scale = (1 - b_center)/ssum at the end
    const float* sp = &s_scale[sg];
    float4v sc[4];
    sc[0] = *(const float4v*)sp;
    sc[1] = *(const float4v*)(sp + 4);
    sc[2] = *(const float4v*)(sp + 8);
    sc[3] = *(const float4v*)(sp + 12);

    size_t ob = ((size_t)(n * D + d) * H + h) * W + gw;
#pragma unroll
    for (int q = 0; q < 4; ++q) {
        float4v o = {acc2[2 * q][0]     * sc[q][0],
                     acc2[2 * q][1]     * sc[q][1],
                     acc2[2 * q + 1][0] * sc[q][2],
                     acc2[2 * q + 1][1] * sc[q][3]};
        *(float4v*)(out + ob + 4 * q) = o;
    }
}

extern "C" void kernel_launch(void* const* d_in, const int* in_sizes, int n_in,
                              void* d_out, int out_size, void* d_ws, size_t ws_size,
                              hipStream_t stream) {
    const float* V        = (const float*)d_in[0];
    const float* boundary = (const float*)d_in[1];
    // d_in[2] = ksize (5), d_in[3] = dilation (3) — fixed, compiled in.
    const float* dist     = (const float*)d_in[4];
    float* out = (float*)d_out;

    int grid = N * H * (D / DCHUNK);   // 1024 blocks
    infuse_kernel<<<grid, 128, 0, stream>>>(V, boundary, dist, out);
}

// Round 3
// 12.805 us; speedup vs baseline: 1.1281x; 1.1281x over previous
//
#include <hip/hip_runtime.h>

// Problem constants (fixed by setup_inputs)
constexpr int N = 2, D = 64, H = 128, W = 128;
constexpr int K = 5, K2 = 25, DIL = 3, PAD = 6;   // pad = (K/2)*DIL
constexpr int DCHUNK = 16;                         // channels per block (1 per thread)
constexpr int HW = H * W;
constexpr int VBYTES = N * D * H * W * 4;          // 8388608
constexpr int SKW = 144;                           // skewed s_att row stride (floats)

typedef float float4v __attribute__((ext_vector_type(4)));
typedef float float2v __attribute__((ext_vector_type(2)));

__device__ __forceinline__ int sidx(int w) { return w + 4 * (w >> 5); }

__device__ __forceinline__ void pk_fma(float2v& d, float2v s0, float2v s1) {
    // packed dual FP32 FMA: d.lo += s0.lo*s1.lo ; d.hi += s0.hi*s1.hi
    asm("v_pk_fma_f32 %0, %1, %2, %0" : "+v"(d) : "v"(s0), "v"(s1));
}

// Phase 1, k in [KLO,KHI): batched clamped loads FIRST (one latency exposure),
// then compute. Stores UNNORMALIZED att (0 at OOB; OOB sim term 1+1e-5 still
// counted in the returned partial sum — matches zero-padded im2col reference).
template<int KLO, int KHI>
__device__ __forceinline__ float phase1_part(const float* __restrict__ bp,
                                             const float* __restrict__ dist,
                                             int h, int w, float* sa) {
    constexpr int KN = KHI - KLO;
    float bvr[KN];
    bool  okk[KN];
#pragma unroll
    for (int kk = 0; kk < KN; ++kk) {
        const int k = KLO + kk, i = k / K, j = k % K;
        int bh = h + i * DIL - PAD;
        int bw = w + j * DIL - PAD;
        okk[kk] = (bh >= 0) & (bh < H) & (bw >= 0) & (bw < W);
        int off = bh * W + bw;
        off = min(max(off, 0), HW - 1);     // v_med3
        bvr[kk] = bp[off];
    }
    float partial = 0.f;
#pragma unroll
    for (int kk = 0; kk < KN; ++kk) {
        const int k = KLO + kk;
        float bv = okk[kk] ? bvr[kk] : 0.f;
        float bm = fminf(fmaxf(bv * dist[k], 0.f), 1.f);
        float s = 1.f - bm + 1e-5f;
        partial += s;
        sa[k * SKW + sidx(w)] = okk[kk] ? s : 0.f;
    }
    return partial;
}

__global__ __launch_bounds__(256, 4)
void infuse_kernel(const float* __restrict__ V,
                   const float* __restrict__ boundary,
                   const float* __restrict__ dist,
                   float* __restrict__ out) {
    // grid = N * H * (D/DCHUNK) = 1024. XCD-chunked bijection (1024 = 8*128):
    // XCD x owns 32 consecutive h -> V slice ~1.4 MB, L2-resident.
    int obid = blockIdx.x;
    int bid  = (obid & 7) * 128 + (obid >> 3);     // bijective
    int dblk = bid & 3;            // channel block (D/DCHUNK = 4)
    int h    = (bid >> 2) & (H - 1);
    int n    = bid >> 9;

    __shared__ float s_att[K2 * SKW];   // 14.4 KB, skewed, UNNORMALIZED
    __shared__ float s_scale[W];

    int tid = threadIdx.x;

    // ---- Phase 0: phase-2 addressing; prefetch window rows 0-1 before
    // phase 1 so their latency hides under the attention compute.
    int g  = tid & 15;             // pixel group: pixels 8g..8g+7
    int c  = tid >> 4;             // channel within chunk
    int d  = dblk * DCHUNK + c;
    int gw = 8 * g;
    int sg = sidx(gw);

    int cb   = (n * D + d) * (H * W * 4);   // channel byte base (fits int)
    int colb = gw * 4 - 32;                  // aligned window base (col gw-8)
    const char* Vb = (const char*)V;

    // Per-chunk offsets clamped into the buffer; any clamping chunk only
    // feeds att=0 positions (OOB rows/cols) — validated scheme.
    float4v vbuf[2][6];
#pragma unroll
    for (int i = 0; i < 2; ++i) {
        int r  = h + i * DIL - PAD;          // may be OOB -> att=0 row
        int rb = cb + r * (W * 4) + colb;
#pragma unroll
        for (int e = 0; e < 6; ++e) {
            int o = rb + 16 * e;
            o = min(max(o, 0), VBYTES - 16);   // v_med3
            vbuf[i][e] = *(const float4v*)(Vb + o);
        }
    }
    __builtin_amdgcn_sched_barrier(0);   // pin: prefetch issued before phase 1

    // ---- Phase 1: single barrier. Threads 0..127 own one pixel each and do
    // all 25 taps (two 13/12 batches -> same fp add order as the 2-half
    // reduction, bit-identical). Threads 128..255 go straight to the barrier;
    // the other 3 blocks/CU cover the idle SIMD slots.
    if (tid < W) {
        int w = tid;
        const float* bp = boundary + n * HW;
        float bc = bp[h * W + w];            // center boundary (for scale)
        float total = phase1_part<0, 13>(bp, dist, h, w, s_att)
                    + phase1_part<13, 25>(bp, dist, h, w, s_att);
        s_scale[w] = (1.f - bc) / total;
    }
    __syncthreads();

    // ---- Phase 2: thread = 8 consecutive pixels x 1 channel.
    // acc held as 4 float2 pairs: (px0,1)(px2,3)(px4,5)(px6,7).
    // Row software pipeline: rows 0,1 prefetched; after consuming row i,
    // issue row i+2 into the freed buffer — a full row of FMA work between
    // issue and first use hides the L2 latency.
    float2v acc2[4] = {{0,0},{0,0},{0,0},{0,0}};

#pragma unroll
    for (int i = 0; i < K; ++i) {
        const float4v (&v)[6] = vbuf[i & 1];   // static index after unroll

#pragma unroll
        for (int j = 0; j < K; ++j) {
            const float* ap = &s_att[(i * K + j) * SKW + sg];
            float4v aLo = *(const float4v*)ap;
            float4v aHi = *(const float4v*)(ap + 4);
            if ((j & 1) == 0) {
                // even j: idx = 2pp + 3j + 2 is even -> adjacent v pairs
#pragma unroll
                for (int pp = 0; pp < 4; ++pp) {
                    const int idx = 2 * pp + 3 * j + 2;   // compile-time, even
                    float2v s0 = {v[idx >> 2][idx & 3],
                                  v[(idx + 1) >> 2][(idx + 1) & 3]};
                    float2v a2 = (pp < 2) ? float2v{aLo[2*pp], aLo[2*pp+1]}
                                          : float2v{aHi[2*pp-4], aHi[2*pp-3]};
                    pk_fma(acc2[pp], s0, a2);
                }
            } else {
                // odd j: misaligned pairs -> scalar
#pragma unroll
                for (int px = 0; px < 8; ++px) {
                    const int idx = px + 3 * j + 2;
                    float a = (px < 4) ? aLo[px & 3] : aHi[px & 3];
                    acc2[px >> 1][px & 1] =
                        fmaf(v[idx >> 2][idx & 3], a, acc2[px >> 1][px & 1]);
                }
            }
        }

        // consume-then-issue: refill the buffer row i occupied with row i+2
        if (i < K - 2) {
            int r  = h + (i + 2) * DIL - PAD;
            int rb = cb + r * (W * 4) + colb;
#pragma unroll
            for (int e = 0; e < 6; ++e) {
                int o = rb + 16 * e;
                o = min(max(o, 0), VBYTES - 16);   // v_med3
                vbuf[i & 1][e] = *(const float4v*)(Vb + o);
            }
        }
    }

    // apply per-pixel scale = (1 - b_center)/ssum at the end
    float4v scLo = *(const float4v*)&s_scale[gw];
    float4v scHi = *(const float4v*)&s_scale[gw + 4];
    float4v o0 = {acc2[0][0] * scLo[0], acc2[0][1] * scLo[1],
                  acc2[1][0] * scLo[2], acc2[1][1] * scLo[3]};
    float4v o1 = {acc2[2][0] * scHi[0], acc2[2][1] * scHi[1],
                  acc2[3][0] * scHi[2], acc2[3][1] * scHi[3]};

    size_t ob = ((size_t)(n * D + d) * H + h) * W + gw;
    *(float4v*)(out + ob)     = o0;
    *(float4v*)(out + ob + 4) = o1;
}

extern "C" void kernel_launch(void* const* d_in, const int* in_sizes, int n_in,
                              void* d_out, int out_size, void* d_ws, size_t ws_size,
                              hipStream_t stream) {
    const float* V        = (const float*)d_in[0];
    const float* boundary = (const float*)d_in[1];
    // d_in[2] = ksize (5), d_in[3] = dilation (3) — fixed, compiled in.
    const float* dist     = (const float*)d_in[4];
    float* out = (float*)d_out;

    int grid = N * H * (D / DCHUNK);   // 1024 blocks
    infuse_kernel<<<grid, 256, 0, stream>>>(V, boundary, dist, out);
}

// Round 4
// 12.383 us; speedup vs baseline: 1.1666x; 1.0341x over previous
//
#include <hip/hip_runtime.h>

// Problem constants (fixed by setup_inputs)
constexpr int N = 2, D = 64, H = 128, W = 128;
constexpr int K = 5, K2 = 25, DIL = 3, PAD = 6;   // pad = (K/2)*DIL
constexpr int DCHUNK = 16;                         // channels per block
constexpr int HW = H * W;
constexpr int VBYTES = N * D * H * W * 4;          // 8388608
constexpr int SK2 = 36;    // per-wave att row stride (floats): 16B-aligned rows,
                           // +4 skew/row -> writes hit all 32 banks 2x (free)
constexpr int WATT = 26 * SK2;   // 25 real rows + 1 trash row (phantom tap k=25)

typedef float float4v __attribute__((ext_vector_type(4)));
typedef float float2v __attribute__((ext_vector_type(2)));

__device__ __forceinline__ void pk_fma(float2v& d, float2v s0, float2v s1) {
    // packed dual FP32 FMA: d.lo += s0.lo*s1.lo ; d.hi += s0.hi*s1.hi
    asm("v_pk_fma_f32 %0, %1, %2, %0" : "+v"(d) : "v"(s0), "v"(s1));
}

__global__ __launch_bounds__(256, 4)
void infuse_kernel(const float* __restrict__ V,
                   const float* __restrict__ boundary,
                   const float* __restrict__ dist,
                   float* __restrict__ out) {
    // grid = N * H * (D/DCHUNK) = 1024. XCD-chunked bijection (1024 = 8*128):
    // XCD x owns 32 consecutive h -> V slice ~1.4 MB, L2-resident.
    int obid = blockIdx.x;
    int bid  = (obid & 7) * 128 + (obid >> 3);     // bijective
    int dblk = bid & 3;            // channel block (D/DCHUNK = 4)
    int h    = (bid >> 2) & (H - 1);
    int n    = bid >> 9;

    // Per-wave private att regions -> ZERO block barriers. Each wave owns
    // 32 pixels x 16 channels end-to-end; phase1 -> lgkmcnt(0) -> phase2.
    __shared__ float s_att[4 * WATT];   // 15.0 KB, scale-folded att

    int tid  = threadIdx.x;
    int wv   = tid >> 6;
    int lane = tid & 63;
    float* watt = &s_att[wv * WATT];

    // ---- Phase-2 mapping (c-major: lanes g=0..3 of one channel store
    // 4x32 B contiguous -> coalesced).
    int g   = lane & 3;             // px group within wave (4 x 8 px)
    int c   = lane >> 2;            // channel within chunk (0..15)
    int d   = dblk * DCHUNK + c;
    int px0 = 32 * wv + 8 * g;      // first of this lane's 8 pixels

    int cb   = (n * D + d) * (H * W * 4);   // channel byte base (fits int)
    int colb = px0 * 4 - 32;                 // aligned window base (col px0-8)
    const char* Vb = (const char*)V;

    // Prefetch window rows 0-1; latency hides under phase-1 compute.
    // Clamp invariant (validated): every 16B chunk is either fully inside
    // att=0 window positions or unclamped.
    float4v pre[2][6];
#pragma unroll
    for (int i = 0; i < 2; ++i) {
        int r  = h + i * DIL - PAD;          // may be OOB -> att=0 row
        int rb = cb + r * (W * 4) + colb;
#pragma unroll
        for (int e = 0; e < 6; ++e) {
            int o = rb + 16 * e;
            o = min(max(o, 0), VBYTES - 16);   // v_med3
            pre[i][e] = *(const float4v*)(Vb + o);
        }
    }
    __builtin_amdgcn_sched_barrier(0);   // pin: prefetch issued before phase 1

    // ---- Phase 1 (wave-local): 64 lanes = 32 px x 2 k-halves, 13 taps each.
    // half=1 handles k=13..24 plus a phantom tap k=25 (masked: contributes 0,
    // stored to the trash row 25). Branchless: per-tap constants selected by
    // cndmask on compile-time values -> no intra-wave divergence.
    {
        int pxl  = lane & 31;              // pixel within wave
        int wpx  = 32 * wv + pxl;          // global col
        int half = lane >> 5;
        const float* bp = boundary + n * HW;
        float bc = bp[h * W + wpx];        // center boundary (for scale)

        float bvr[13];
        bool  ok[13];
#pragma unroll
        for (int kk = 0; kk < 13; ++kk) {
            const int iA = kk / 5,        jA = kk % 5;
            const int iB = (kk + 13) / 5, jB = (kk + 13) % 5;  // kk=12 -> k=25
            int idel = half ? (iB * DIL - PAD) : (iA * DIL - PAD);
            int jdel = half ? (jB * DIL - PAD) : (jA * DIL - PAD);
            int bh = h + idel;
            int bw = wpx + jdel;
            bool inb = (bh >= 0) & (bh < H) & (bw >= 0) & (bw < W);
            if (kk == 12) inb = inb & (half == 0);   // phantom tap
            ok[kk] = inb;
            int off = bh * W + bw;
            off = min(max(off, 0), HW - 1);          // v_med3
            bvr[kk] = bp[off];
        }
        float sv[13];
        float partial = 0.f;
#pragma unroll
        for (int kk = 0; kk < 13; ++kk) {
            float dA = dist[kk];
            float dB = (kk < 12) ? dist[kk + 13] : 0.f;
            float dk = half ? dB : dA;
            float bv = ok[kk] ? bvr[kk] : 0.f;
            float bm = fminf(fmaxf(bv * dk, 0.f), 1.f);
            float s  = 1.f - bm + 1e-5f;
            // phantom adds +0.f (bitwise no-op on a positive partial)
            partial += (kk == 12) ? (half ? 0.f : s) : s;
            sv[kk] = s;
        }
        // cross-half sum: a+b bitwise == b+a -> both halves get the exact
        // same total (same order as R0's s_psum[0]+s_psum[1]).
        float other = __shfl_xor(partial, 32);
        float total = partial + other;
        float scale = (1.f - bc) / total;
        // write scale-folded att (normalization + (1-bc) baked in)
        float* sb = watt + half * 13 * SK2 + pxl;
#pragma unroll
        for (int kk = 0; kk < 13; ++kk)
            sb[kk * SK2] = ok[kk] ? sv[kk] * scale : 0.f;
    }
    // Wave-local producer->consumer: program order + lgkmcnt(0) makes all 64
    // lanes' ds_writes visible to this wave's ds_reads. No cross-wave deps.
    asm volatile("s_waitcnt lgkmcnt(0)" ::: "memory");
    __builtin_amdgcn_sched_barrier(0);

    // ---- Phase 2: thread = 8 consecutive pixels x 1 channel.
    // acc held as 4 float2 pairs: (px0,1)(px2,3)(px4,5)(px6,7).
    float2v acc2[4] = {{0,0},{0,0},{0,0},{0,0}};
    const float* ar = watt + 8 * g;   // + (i*5+j)*SK2 folds to imm offsets

#pragma unroll
    for (int i = 0; i < K; ++i) {
        float4v v[6];
        if (i < 2) {
#pragma unroll
            for (int e = 0; e < 6; ++e) v[e] = pre[i][e];
        } else {
            int r  = h + i * DIL - PAD;
            int rb = cb + r * (W * 4) + colb;
#pragma unroll
            for (int e = 0; e < 6; ++e) {
                int o = rb + 16 * e;
                o = min(max(o, 0), VBYTES - 16);   // v_med3
                v[e] = *(const float4v*)(Vb + o);
            }
        }
#pragma unroll
        for (int j = 0; j < K; ++j) {
            const float* ap = ar + (i * K + j) * SK2;
            float4v aLo = *(const float4v*)ap;
            float4v aHi = *(const float4v*)(ap + 4);
            if ((j & 1) == 0) {
                // even j: idx = 2pp + 3j + 2 is even -> adjacent v pairs
#pragma unroll
                for (int pp = 0; pp < 4; ++pp) {
                    const int idx = 2 * pp + 3 * j + 2;   // compile-time, even
                    float2v s0 = {v[idx >> 2][idx & 3],
                                  v[(idx + 1) >> 2][(idx + 1) & 3]};
                    float2v a2 = (pp < 2) ? float2v{aLo[2*pp], aLo[2*pp+1]}
                                          : float2v{aHi[2*pp-4], aHi[2*pp-3]};
                    pk_fma(acc2[pp], s0, a2);
                }
            } else {
                // odd j: misaligned pairs -> scalar
#pragma unroll
                for (int px = 0; px < 8; ++px) {
                    const int idx = px + 3 * j + 2;
                    float a = (px < 4) ? aLo[px & 3] : aHi[px & 3];
                    acc2[px >> 1][px & 1] =
                        fmaf(v[idx >> 2][idx & 3], a, acc2[px >> 1][px & 1]);
                }
            }
        }
    }

    // scale already folded into att -> straight store
    float4v o0 = {acc2[0][0], acc2[0][1], acc2[1][0], acc2[1][1]};
    float4v o1 = {acc2[2][0], acc2[2][1], acc2[3][0], acc2[3][1]};

    size_t ob = ((size_t)(n * D + d) * H + h) * W + px0;
    *(float4v*)(out + ob)     = o0;
    *(float4v*)(out + ob + 4) = o1;
}

extern "C" void kernel_launch(void* const* d_in, const int* in_sizes, int n_in,
                              void* d_out, int out_size, void* d_ws, size_t ws_size,
                              hipStream_t stream) {
    const float* V        = (const float*)d_in[0];
    const float* boundary = (const float*)d_in[1];
    // d_in[2] = ksize (5), d_in[3] = dilation (3) — fixed, compiled in.
    const float* dist     = (const float*)d_in[4];
    float* out = (float*)d_out;

    int grid = N * H * (D / DCHUNK);   // 1024 blocks
    infuse_kernel<<<grid, 256, 0, stream>>>(V, boundary, dist, out);
}